// Round 1
// baseline (213.792 us; speedup 1.0000x reference)
//
#include <hip/hip_runtime.h>

// GridGraph adjacency (COO) for all-active 2048x2048 rook grid.
// Output layout (float32): [vals(4N) | rows(4N) | cols(4N)], direction-major
// within each: d*N + p, d in ROOK order (down, up, right, left).

constexpr int HH = 2048;
constexpr int WW = 2048;
constexpr long long NN = (long long)HH * WW;

__global__ __launch_bounds__(256) void grid_adj_kernel(
    const float* __restrict__ w, float* __restrict__ out)
{
    const int t = blockIdx.x * blockDim.x + threadIdx.x;
    const int p = t << 2;                 // first of 4 consecutive elements
    const int i = p >> 11;                // p / W  (W = 2048)
    const int j = p & (WW - 1);           // p % W

    float* __restrict__ vals = out;
    float* __restrict__ rows = out + 4 * NN;
    float* __restrict__ cols = out + 8 * NN;

    const float fp0 = (float)p;
    const float4 pf = make_float4(fp0, fp0 + 1.f, fp0 + 2.f, fp0 + 3.f);
    const float4 z4 = make_float4(0.f, 0.f, 0.f, 0.f);

    // d = 0: down (i+1, j)  — validity wave-uniform per row
    {
        float4 v = z4, r = z4, c = z4;
        if (i + 1 < HH) {
            const int q = p + WW;
            v = *(const float4*)(w + q);          // aligned 16B load
            r = pf;
            const float fq = (float)q;
            c = make_float4(fq, fq + 1.f, fq + 2.f, fq + 3.f);
        }
        *(float4*)(vals + p) = v;
        *(float4*)(rows + p) = r;
        *(float4*)(cols + p) = c;
    }

    // d = 1: up (i-1, j)
    {
        float4 v = z4, r = z4, c = z4;
        if (i >= 1) {
            const int q = p - WW;
            v = *(const float4*)(w + q);          // aligned 16B load
            r = pf;
            const float fq = (float)q;
            c = make_float4(fq, fq + 1.f, fq + 2.f, fq + 3.f);
        }
        const long long o = NN + p;
        *(float4*)(vals + o) = v;
        *(float4*)(rows + o) = r;
        *(float4*)(cols + o) = c;
    }

    // d = 2: right (i, j+1) — element k neighbor = p+k+1; only k=3 at j==W-4 invalid
    {
        const int q = p + 1;
        const bool last4 = (j == WW - 4);
        const float w0 = w[q], w1 = w[q + 1], w2 = w[q + 2];
        float w3 = 0.f, r3 = 0.f, c3 = 0.f;
        if (!last4) {                              // guard also prevents OOB read at p+4==N
            w3 = w[q + 3];
            r3 = pf.w;
            c3 = (float)(q + 3);
        }
        const float fq = (float)q;
        const long long o = 2 * NN + p;
        *(float4*)(vals + o) = make_float4(w0, w1, w2, w3);
        *(float4*)(rows + o) = make_float4(pf.x, pf.y, pf.z, r3);
        *(float4*)(cols + o) = make_float4(fq, fq + 1.f, fq + 2.f, c3);
    }

    // d = 3: left (i, j-1) — element k neighbor = p+k-1; only k=0 at j==0 invalid
    {
        const bool first4 = (j == 0);
        float w0 = 0.f, r0 = 0.f, c0 = 0.f;
        if (!first4) {                             // guard also prevents OOB read at p==0
            w0 = w[p - 1];
            r0 = pf.x;
            c0 = (float)(p - 1);
        }
        const float w1 = w[p], w2 = w[p + 1], w3 = w[p + 2];
        const long long o = 3 * NN + p;
        *(float4*)(vals + o) = make_float4(w0, w1, w2, w3);
        *(float4*)(rows + o) = make_float4(r0, pf.y, pf.z, pf.w);
        *(float4*)(cols + o) = make_float4(c0, fp0, fp0 + 1.f, fp0 + 2.f);
    }
}

extern "C" void kernel_launch(void* const* d_in, const int* in_sizes, int n_in,
                              void* d_out, int out_size, void* d_ws, size_t ws_size,
                              hipStream_t stream) {
    // d_in[0] = activities (all-true bool, unused), d_in[1] = vertex_weights f32 [H*W]
    const float* w = (const float*)d_in[1];
    float* out = (float*)d_out;

    const int threads = 256;
    const int total_threads = (int)(NN / 4);       // 1,048,576 threads, 4 elems each
    const int blocks = total_threads / threads;    // 4096 blocks
    grid_adj_kernel<<<blocks, threads, 0, stream>>>(w, out);
}